// Round 18
// baseline (401.360 us; speedup 1.0000x reference)
//
#include <hip/hip_runtime.h>
#include <stdint.h>
#include <math.h>

#define DD 1024
#define SS 1000
#define BB 8
#define HH 16
#define MIDD 4096
#define OUTD 1000

typedef unsigned short u16;
typedef __attribute__((ext_vector_type(4))) float f32x4;
typedef __attribute__((ext_vector_type(4))) unsigned int u32x4;

__device__ __forceinline__ u16 f2b(float f) {
    union { float f; uint32_t u; } v; v.f = f;
    uint32_t r = v.u + 0x7fffu + ((v.u >> 16) & 1u);
    return (u16)(r >> 16);
}
__device__ __forceinline__ float b2f(u16 b) {
    union { uint32_t u; float f; } v; v.u = ((uint32_t)b) << 16; return v.f;
}

// swizzled element offset for 64-elem (128B) rows: XOR 16B-chunk with row&7
__device__ __forceinline__ int sz64(int row, int e) {
    return row * 64 + ((((e >> 3) ^ row) & 7) << 3) + (e & 7);
}

__device__ __forceinline__ void mfma_b16(f32x4& d, u32x4 a, u32x4 b) {
    asm("v_mfma_f32_16x16x32_bf16 %0, %1, %2, %0" : "+v"(d) : "v"(a), "v"(b));
}
#define MFMA_FENCE() do { __builtin_amdgcn_sched_barrier(0); \
    asm volatile("s_nop 7\n\ts_nop 7\n\ts_nop 7" ::); \
    __builtin_amdgcn_sched_barrier(0); } while (0)

#define GLDS16(gp, lp) \
    __builtin_amdgcn_global_load_lds((const __attribute__((address_space(1))) uint32_t*)(gp), \
                                     (__attribute__((address_space(3))) uint32_t*)(lp), 16, 0, 0)

// XCD swizzle helper (m204 bijective form)
__device__ __forceinline__ int xcd_swz(int orig, int nwg) {
    const int q8 = nwg >> 3, r8 = nwg & 7, xc = orig & 7;
    return (xc < r8 ? xc * (q8 + 1) : r8 * (q8 + 1) + (xc - r8) * q8) + (orig >> 3);
}

// wg -> (bm_tile, bn_tile). ORDER 0: n-fastest. ORDER 1: m-fastest. ORDER 2: grouped.
template<int ORDER, int GM>
__device__ __forceinline__ void decode_wg(int wg, int tiles, int& mt, int& nt) {
    if (ORDER == 0)      { mt = wg / tiles; nt = wg % tiles; }
    else if (ORDER == 1) { mt = wg % tiles; nt = wg / tiles; }
    else {
        const int gsz = GM * tiles;
        const int grp = wg / gsz, idx = wg % gsz;
        nt = idx % tiles; mt = grp * GM + idx / tiles;
    }
}

// ---------------- prep: posenc + ALL weight transposes in ONE launch ----------------
// blockIdx.y: 0=Wq(scaled) 1=Wk 2=Wv 3=Wo 4=W1 5=W2 6=posenc. Early-exit oversize x.
__global__ void k_prep(const float* __restrict__ x, u16* __restrict__ xpe,
                       const float* __restrict__ Wq, const float* __restrict__ Wk,
                       const float* __restrict__ Wv, const float* __restrict__ Wo,
                       const float* __restrict__ W1, const float* __restrict__ W2,
                       u16* __restrict__ Wqkvt, u16* __restrict__ Wot,
                       u16* __restrict__ W1t, u16* __restrict__ W2t, float qscale) {
    const int id = blockIdx.y;
    const int tid = threadIdx.y * 32 + threadIdx.x;
    if (id == 6) {   // posenc add + bf16 cast (pair-wise)
        long p = (long)blockIdx.x * 256 + tid;
        if (p >= (long)BB * SS * DD / 2) return;
        int dp = (int)(p & (DD / 2 - 1));
        int s = (int)((p >> 9) % SS);
        float dv = __expf((float)(2 * dp) * (-9.210340371976184f / (float)DD));
        float sn, cs;
        sincosf((float)s * dv, &sn, &cs);
        float2 xv = *(const float2*)&x[p * 2];
        uint32_t pk = (uint32_t)f2b(xv.x + sn) | ((uint32_t)f2b(xv.y + cs) << 16);
        ((uint32_t*)xpe)[p] = pk;
        return;
    }
    const float* W; u16* Wt; int R, C; float scale = 1.f;
    if (id == 0)      { W = Wq; Wt = Wqkvt;            R = 1024; C = 1024; scale = qscale; }
    else if (id == 1) { W = Wk; Wt = Wqkvt + 1048576;  R = 1024; C = 1024; }
    else if (id == 2) { W = Wv; Wt = Wqkvt + 2097152;  R = 1024; C = 1024; }
    else if (id == 3) { W = Wo; Wt = Wot;              R = 1024; C = 1024; }
    else if (id == 4) { W = W1; Wt = W1t;              R = 1024; C = 4096; }
    else              { W = W2; Wt = W2t;              R = 4096; C = 1024; }
    const int tilesx = C >> 5;
    const int ntile = (R >> 5) * tilesx;
    if (blockIdx.x >= (unsigned)ntile) return;
    const int bc = (blockIdx.x % tilesx) * 32, br = (blockIdx.x / tilesx) * 32;
    __shared__ float tile[32][33];
    int tx = threadIdx.x, ty = threadIdx.y;
#pragma unroll
    for (int i = 0; i < 32; i += 8)
        tile[ty + i][tx] = W[(long)(br + ty + i) * C + bc + tx];
    __syncthreads();
#pragma unroll
    for (int i = 0; i < 32; i += 8)
        Wt[(long)(bc + ty + i) * R + br + tx] = f2b(tile[tx][ty + i] * scale);
}

// ---------------- bf16 GEMM (8-wave, BN=256): C = A * Bt^T ----------------
// BM=128: 3-buf LDS (144KB), 2 tiles in flight, vmcnt(6).
// BM=256: 2-buf (128KB); FULL next tile (A+B, 8 loads) issued at loop top -> vmcnt(8).
// All LDS rows 128B with sz64 both-sides swizzle -> 0 bank conflicts (r15 lesson).
template<int MODE, int BM, int ORDER, int GM>
__global__ __launch_bounds__(512)
void k_gemm(const u16* __restrict__ A, const u16* __restrict__ Bt, void* __restrict__ Cp,
            const float* __restrict__ bias, const u16* res,
            int M, int N, int K, int lda, int ldb, int ldc, int tiles)
{
    constexpr int MF = BM / 32;
    constexpr int AL = BM / 64;
    constexpr int NBUF = (BM == 128) ? 3 : 2;
    __shared__ u16 SA[NBUF][BM * 64];
    __shared__ u16 SB[NBUF][256 * 64];
    const int t = threadIdx.x, lane = t & 63, w = t >> 6;
    const int lr = lane & 15, g = lane >> 4;
    const int wm = w >> 2, wn = w & 3;

    const int wg = xcd_swz(blockIdx.x, gridDim.x);
    int mt, ntl;
    decode_wg<ORDER, GM>(wg, tiles, mt, ntl);
    const int bm = mt * BM, bn = ntl * 256;

    const int srow8 = lane >> 3;
    const int csrc = ((lane & 7) ^ srow8) << 3;
    const u16* ga[AL];
    const u16* gb[4];
#pragma unroll
    for (int l = 0; l < AL; ++l) {
        int r = bm + w * (BM / 8) + l * 8 + srow8;
        if (r >= M) r = M - 1;
        ga[l] = A + (long)r * lda + csrc;
    }
#pragma unroll
    for (int l = 0; l < 4; ++l)
        gb[l] = Bt + (long)(bn + w * 32 + l * 8 + srow8) * ldb + csrc;

#define STAGE_A(buf, k0) do { \
        _Pragma("unroll") \
        for (int l = 0; l < AL; ++l) \
            GLDS16(ga[l] + (k0), &SA[buf][(w * (BM / 8) + l * 8) * 64]); \
    } while (0)
#define STAGE_B(buf, k0) do { \
        _Pragma("unroll") \
        for (int l = 0; l < 4; ++l) \
            GLDS16(gb[l] + (k0), &SB[buf][(w * 32 + l * 8) * 64]); \
    } while (0)

    f32x4 acc[MF][4] = {};

#define PH(buf, kk) do { \
        u32x4 av[MF], bv[4]; \
        _Pragma("unroll") \
        for (int m = 0; m < MF; ++m) \
            av[m] = *(const u32x4*)&SA[buf][sz64(wm * (BM / 2) + m * 16 + lr, (kk) * 32 + g * 8)]; \
        _Pragma("unroll") \
        for (int n = 0; n < 4; ++n) \
            bv[n] = *(const u32x4*)&SB[buf][sz64(wn * 64 + n * 16 + lr, (kk) * 32 + g * 8)]; \
        __builtin_amdgcn_s_setprio(1); \
        _Pragma("unroll") \
        for (int m = 0; m < MF; ++m) \
            _Pragma("unroll") \
            for (int n = 0; n < 4; ++n) \
                mfma_b16(acc[m][n], av[m], bv[n]); \
        __builtin_amdgcn_s_setprio(0); \
    } while (0)

    const int nt = K >> 6;

    if constexpr (NBUF == 3) {
        STAGE_A(0, 0); STAGE_B(0, 0);
        STAGE_A(1, 64); STAGE_B(1, 64);
        int cb = 0, sb = 2;
        for (int tt = 0; tt < nt; ++tt) {
            if (tt + 1 < nt) asm volatile("s_waitcnt vmcnt(6)" ::: "memory");
            else             asm volatile("s_waitcnt vmcnt(0)" ::: "memory");
            __builtin_amdgcn_s_barrier();
            if (tt + 2 < nt) { STAGE_A(sb, (tt + 2) << 6); STAGE_B(sb, (tt + 2) << 6); }
            PH(cb, 0);
            PH(cb, 1);
            cb = (cb == 2) ? 0 : cb + 1;
            sb = (sb == 2) ? 0 : sb + 1;
        }
    } else {
        // 2-buf, full-tile issue at top: ledger = 8 (tile tt) + 8 (tile tt+1) -> vmcnt(8)
        STAGE_A(0, 0); STAGE_B(0, 0);
        for (int tt = 0; tt < nt; ++tt) {
            const int cb2 = tt & 1, nb = cb2 ^ 1, kn = (tt + 1) << 6;
            if (tt + 1 < nt) {
                STAGE_A(nb, kn); STAGE_B(nb, kn);
                asm volatile("s_waitcnt vmcnt(8)" ::: "memory");
            } else {
                asm volatile("s_waitcnt vmcnt(0)" ::: "memory");
            }
            __builtin_amdgcn_s_barrier();
            PH(cb2, 0);
            PH(cb2, 1);
            __builtin_amdgcn_s_barrier();
        }
    }
#undef PH
#undef STAGE_A
#undef STAGE_B

    MFMA_FENCE();

#pragma unroll
    for (int m = 0; m < MF; ++m) {
#pragma unroll
        for (int j = 0; j < 4; ++j) {
            const int r = bm + wm * (BM / 2) + m * 16 + g * 4 + j;
            if (r >= M) continue;
            const long ro = (long)r * ldc;
#pragma unroll
            for (int n = 0; n < 4; ++n) {
                const int c = bn + wn * 64 + n * 16 + lr;
                float v = acc[m][n][j];
                if (MODE == 0)      ((float*)Cp)[ro + c] = v;
                else if (MODE == 1) ((u16*)Cp)[ro + c] = f2b(v);
                else if (MODE == 2) { v += bias[c]; ((u16*)Cp)[ro + c] = f2b(v > 0.f ? v : 0.f); }
                else                { v += bias[c] + b2f(res[ro + c]); ((u16*)Cp)[ro + c] = f2b(v); }
            }
        }
    }
}

// ---------------- bf16 GEMM (4-wave, 128x128, BK=64, 64KB LDS -> 2 blocks/CU) ----------------
template<int MODE, int ORDER, int GM>
__global__ __launch_bounds__(256)
void k_gemm4(const u16* __restrict__ A, const u16* __restrict__ Bt, void* __restrict__ Cp,
             const float* __restrict__ bias, const u16* res,
             int M, int N, int K, int lda, int ldb, int ldc, int tiles)
{
    __shared__ u16 SA[2][128 * 64];   // 32 KB
    __shared__ u16 SB[2][128 * 64];   // 32 KB
    const int t = threadIdx.x, lane = t & 63, w = t >> 6;   // 4 waves
    const int lr = lane & 15, g = lane >> 4;
    const int wm = w >> 1, wn = w & 1;

    const int wg = xcd_swz(blockIdx.x, gridDim.x);
    int mt, ntl;
    decode_wg<ORDER, GM>(wg, tiles, mt, ntl);
    const int bm = mt * 128, bn = ntl * 128;

    const int srow8 = lane >> 3;
    const int csrc = ((lane & 7) ^ srow8) << 3;
    const u16* ga[4];
    const u16* gb[4];
#pragma unroll
    for (int l = 0; l < 4; ++l) {
        int r = bm + w * 32 + l * 8 + srow8;
        if (r >= M) r = M - 1;
        ga[l] = A + (long)r * lda + csrc;
        gb[l] = Bt + (long)(bn + w * 32 + l * 8 + srow8) * ldb + csrc;
    }

#define STAGE_A(buf, k0) do { \
        _Pragma("unroll") \
        for (int l = 0; l < 4; ++l) \
            GLDS16(ga[l] + (k0), &SA[buf][(w * 32 + l * 8) * 64]); \
    } while (0)
#define STAGE_B(buf, k0) do { \
        _Pragma("unroll") \
        for (int l = 0; l < 4; ++l) \
            GLDS16(gb[l] + (k0), &SB[buf][(w * 32 + l * 8) * 64]); \
    } while (0)

    f32x4 acc[4][4] = {};

#define PH(buf, kk) do { \
        u32x4 av[4], bv[4]; \
        _Pragma("unroll") \
        for (int m = 0; m < 4; ++m) \
            av[m] = *(const u32x4*)&SA[buf][sz64(wm * 64 + m * 16 + lr, (kk) * 32 + g * 8)]; \
        _Pragma("unroll") \
        for (int n = 0; n < 4; ++n) \
            bv[n] = *(const u32x4*)&SB[buf][sz64(wn * 64 + n * 16 + lr, (kk) * 32 + g * 8)]; \
        __builtin_amdgcn_s_setprio(1); \
        _Pragma("unroll") \
        for (int m = 0; m < 4; ++m) \
            _Pragma("unroll") \
            for (int n = 0; n < 4; ++n) \
                mfma_b16(acc[m][n], av[m], bv[n]); \
        __builtin_amdgcn_s_setprio(0); \
    } while (0)

    const int nt = K >> 6;

    STAGE_A(0, 0); STAGE_B(0, 0);
    for (int tt = 0; tt < nt; ++tt) {
        const int cb = tt & 1, nb = cb ^ 1, kn = (tt + 1) << 6;
        if (tt + 1 < nt) {
            STAGE_A(nb, kn); STAGE_B(nb, kn);
            asm volatile("s_waitcnt vmcnt(8)" ::: "memory");
        } else {
            asm volatile("s_waitcnt vmcnt(0)" ::: "memory");
        }
        __builtin_amdgcn_s_barrier();
        PH(cb, 0);
        PH(cb, 1);
        __builtin_amdgcn_s_barrier();
    }
#undef PH
#undef STAGE_A
#undef STAGE_B

    MFMA_FENCE();

#pragma unroll
    for (int m = 0; m < 4; ++m) {
#pragma unroll
        for (int j = 0; j < 4; ++j) {
            const int r = bm + wm * 64 + m * 16 + g * 4 + j;
            if (r >= M) continue;
            const long ro = (long)r * ldc;
#pragma unroll
            for (int n = 0; n < 4; ++n) {
                const int c = bn + wn * 64 + n * 16 + lr;
                float v = acc[m][n][j];
                if (MODE == 0)      ((float*)Cp)[ro + c] = v;
                else if (MODE == 1) ((u16*)Cp)[ro + c] = f2b(v);
                else if (MODE == 2) { v += bias[c]; ((u16*)Cp)[ro + c] = f2b(v > 0.f ? v : 0.f); }
                else                { v += bias[c] + b2f(res[ro + c]); ((u16*)Cp)[ro + c] = f2b(v); }
            }
        }
    }
}

// ---------------- V part of QKV -> Vt [B*H][64][1024] (zero-pad s>=1000) ----------------
__global__ void k_vt(const u16* __restrict__ QKV, u16* __restrict__ Vt) {
    __shared__ u16 tile[128][80];
    int b = blockIdx.z, h = blockIdx.y, s0 = blockIdx.x * 128;
    int t = threadIdx.x;
    int rr = t >> 3, cc = (t & 7) * 8;
#pragma unroll
    for (int p = 0; p < 4; ++p) {
        int s = s0 + p * 32 + rr;
        uint4 val = make_uint4(0u, 0u, 0u, 0u);
        if (s < SS) val = *(const uint4*)&QKV[((long)(b * SS + s)) * 3072 + 2048 + h * 64 + cc];
        *(uint4*)&tile[p * 32 + rr][cc] = val;
    }
    __syncthreads();
    int d = t >> 2, sg = (t & 3) * 32;
    long base = ((long)((b * HH + h) * 64 + d)) * 1024 + s0 + sg;
#pragma unroll
    for (int i = 0; i < 4; ++i) {
        u16 tmp[8];
#pragma unroll
        for (int jj = 0; jj < 8; ++jj) tmp[jj] = tile[sg + i * 8 + jj][d];
        *(uint4*)&Vt[base + i * 8] = *(uint4*)tmp;
    }
}

// ---------------- fused flash attention, FIXED-MAX + SWAPPED QK^T ----------------
__global__ __launch_bounds__(256)
void k_flash(const u16* __restrict__ QKV, const u16* __restrict__ Vt, u16* __restrict__ ctx)
{
    __shared__ u16 Ps[128 * 64];
    __shared__ u16 Ks[64 * 64];
    __shared__ u16 Vs[64 * 64];
    __shared__ u16 Vones[16 * 64];
    const int t = threadIdx.x, lane = t & 63, wave = t >> 6;
    const int lr = lane & 15, g = lane >> 4;
    const int f = blockIdx.x;
    const int bh = (f & 7) + ((f >> 6) << 3);
    const int q0 = ((f >> 3) & 7) * 128;
    const int h = bh & 15, b = bh >> 4;
    const u16* Qg = QKV + (long)b * SS * 3072 + h * 64;
    const u16* Kg = Qg + 1024;
    const u16* Vg = Vt + (long)bh * 65536;

    const int sr8 = wave * 8 + (lane >> 3);
    const int ssrc = ((lane & 7) ^ (lane >> 3)) * 8;
    const int ldst0 = sr8 * 64 + (lane & 7) * 8;
    const int ldst1 = (32 + sr8) * 64 + (lane & 7) * 8;

#pragma unroll
    for (int r = 0; r < 4; ++r) {
        int qr = q0 + r * 32 + sr8; if (qr >= SS) qr = SS - 1;
        GLDS16(Qg + (long)qr * 3072 + ssrc, &Ps[(r * 32 + wave * 8) * 64]);
    }

    u32x4 kr0, kr1, vr0, vr1;
    {
        kr0 = *(const u32x4*)(Kg + (long)sr8 * 3072 + ssrc);
        kr1 = *(const u32x4*)(Kg + (long)(32 + sr8) * 3072 + ssrc);
        vr0 = *(const u32x4*)(Vg + (long)sr8 * 1024 + ssrc);
        vr1 = *(const u32x4*)(Vg + (long)(32 + sr8) * 1024 + ssrc);
    }

    __syncthreads();
    u32x4 qa[2][2];
#pragma unroll
    for (int m = 0; m < 2; ++m)
#pragma unroll
        for (int ks = 0; ks < 2; ++ks)
            qa[m][ks] = *(const u32x4*)&Ps[sz64(wave * 32 + m * 16 + lr, ks * 32 + g * 8)];

    *(u32x4*)&Ks[ldst0] = kr0;
    *(u32x4*)&Ks[ldst1] = kr1;
    *(u32x4*)&Vs[ldst0] = vr0;
    *(u32x4*)&Vs[ldst1] = vr1;
    for (int i = t; i < 16 * 64; i += 256)
        Vones[sz64(i >> 6, i & 63)] = ((i >> 6) == 0) ? (u16)0x3F80 : (u16)0;
    __syncthreads();

    f32x4 o[2][5] = {};

    for (int tt = 0; tt < 16; ++tt) {
        const int kt = tt * 64;
        if (tt < 15) {
            int a0 = kt + 64 + sr8;      if (a0 >= SS) a0 = SS - 1;
            int a1 = kt + 64 + 32 + sr8; if (a1 >= SS) a1 = SS - 1;
            kr0 = *(const u32x4*)(Kg + (long)a0 * 3072 + ssrc);
            kr1 = *(const u32x4*)(Kg + (long)a1 * 3072 + ssrc);
            vr0 = *(const u32x4*)(Vg + (long)sr8 * 1024 + kt + 64 + ssrc);
            vr1 = *(const u32x4*)(Vg + (long)(32 + sr8) * 1024 + kt + 64 + ssrc);
        }

        // swapped QK^T: s[n][m] = C[k = n*16+g*4+j][q = wave*32+m*16+lr]
        f32x4 s[4][2] = {};
#pragma unroll
        for (int ks = 0; ks < 2; ++ks) {
            u32x4 kb[4];
#pragma unroll
            for (int n = 0; n < 4; ++n)
                kb[n] = *(const u32x4*)&Ks[sz64(n * 16 + lr, ks * 32 + g * 8)];
            __builtin_amdgcn_s_setprio(1);
#pragma unroll
            for (int n = 0; n < 4; ++n)
#pragma unroll
                for (int m = 0; m < 2; ++m)
                    mfma_b16(s[n][m], kb[n], qa[m][ks]);
            __builtin_amdgcn_s_setprio(0);
        }
        MFMA_FENCE();

        if (tt == 15) {
#pragma unroll
            for (int n = 0; n < 4; ++n) {
                const int kbase = kt + n * 16 + g * 4;
#pragma unroll
                for (int j = 0; j < 4; ++j)
                    if (kbase + j >= SS) { s[n][0][j] = -1e30f; s[n][1][j] = -1e30f; }
            }
        }

        // P = exp2(s); consecutive k per thread -> pack pairs, ONE b64 store per (m,n)
#pragma unroll
        for (int m = 0; m < 2; ++m) {
            const int prow = wave * 32 + m * 16 + lr;
#pragma unroll
            for (int n = 0; n < 4; ++n) {
                float p0 = exp2f(s[n][m][0]);
                float p1 = exp2f(s[n][m][1]);
                float p2 = exp2f(s[n][m][2]);
                float p3 = exp2f(s[n][m][3]);
                uint32_t pk01, pk23;
                asm("v_cvt_pk_bf16_f32 %0, %1, %2" : "=v"(pk01) : "v"(p0), "v"(p1));
                asm("v_cvt_pk_bf16_f32 %0, %1, %2" : "=v"(pk23) : "v"(p2), "v"(p3));
                *(uint2*)&Ps[sz64(prow, n * 16 + g * 4)] = make_uint2(pk01, pk23);
            }
        }

        asm volatile("s_waitcnt lgkmcnt(0)" ::: "memory");
        __builtin_amdgcn_sched_barrier(0);

        // PV: o += P * V   (nd=4 reads the ones block -> denominator)
#pragma unroll
        for (int m = 0; m < 2; ++m) {
            u32x4 pa0 = *(const u32x4*)&Ps[sz64(wave * 32 + m * 16 + lr, g * 8)];
            u32x4 pa1 = *(const u32x4*)&Ps[sz64(wave * 32 + m * 16 + lr, 32 + g * 8)];
            __builtin_amdgcn_s_setprio(1);
#pragma unroll
            for (int nd = 0; nd < 4; ++nd) {
                u32x4 vb0 = *(const u32x4*)&Vs[sz64(nd * 16 + lr, g * 8)];
                u32x4 vb1 = *(const u32x4*)&Vs[sz64(nd * 16 + lr, 32 + g * 8)];
                mfma_b16(o[m][nd], pa0, vb0);
                mfma_b16(o[m][nd], pa1, vb1);
            }
            {
                u32x4 vb0 = *(const u32x4*)&Vones[sz64(lr, g * 8)];
                u32x4 vb1 = *(const u32x4*)&Vones[sz64(lr, 32 + g * 8)];
                mfma_b16(o[m][4], pa0, vb0);
                mfma_b16(o[m][4], pa1, vb1);
            }
            __builtin_amdgcn_s_setprio(0);
        }

        if (tt < 15) {
            __syncthreads();
            *(u32x4*)&Ks[ldst0] = kr0;
            *(u32x4*)&Ks[ldst1] = kr1;
            *(u32x4*)&Vs[ldst0] = vr0;
            *(u32x4*)&Vs[ldst1] = vr1;
            __syncthreads();
        }
    }

    MFMA_FENCE();

#pragma unroll
    for (int m = 0; m < 2; ++m)
#pragma unroll
        for (int j = 0; j < 4; ++j) {
            const int r = q0 + wave * 32 + m * 16 + g * 4 + j;
            if (r >= SS) continue;
            const float lval = __shfl(o[m][4][j], lane & 48);
            const float inv = 1.0f / lval;
#pragma unroll
            for (int nd = 0; nd < 4; ++nd)
                ctx[((long)b * SS + r) * 1024 + h * 64 + nd * 16 + lr] = f2b(o[m][nd][j] * inv);
        }
}

// ---------------- LN stats bf16 input (vectorized) ----------------
__global__ void k_stats1b(const u16* __restrict__ X, float* __restrict__ part) {
    int b = blockIdx.y, blk = blockIdx.x, t = threadIdx.x;
    const uint4* xp = (const uint4*)(X + (long)b * (SS * DD));
    float s = 0.f, q = 0.f;
    for (int i = blk * 256 + t; i < SS * DD / 8; i += 128 * 256) {
        uint4 v = xp[i];
        uint32_t w[4] = { v.x, v.y, v.z, v.w };
#pragma unroll
        for (int jj = 0; jj < 4; ++jj) {
            float a = b2f((u16)(w[jj] & 0xffff)), c = b2f((u16)(w[jj] >> 16));
            s += a + c; q += a * a + c * c;
        }
    }
#pragma unroll
    for (int o = 32; o; o >>= 1) { s += __shfl_xor(s, o, 64); q += __shfl_xor(q, o, 64); }
    __shared__ float rs[4], rq[4];
    if ((t & 63) == 0) { rs[t >> 6] = s; rq[t >> 6] = q; }
    __syncthreads();
    if (t == 0) {
        part[(b * 128 + blk) * 2]     = rs[0] + rs[1] + rs[2] + rs[3];
        part[(b * 128 + blk) * 2 + 1] = rq[0] + rq[1] + rq[2] + rq[3];
    }
}

__global__ void k_stats2(const float* __restrict__ part, float* __restrict__ st) {
    int b = blockIdx.x, t = threadIdx.x;
    float s = part[(b * 128 + t) * 2], q = part[(b * 128 + t) * 2 + 1];
#pragma unroll
    for (int o = 32; o; o >>= 1) { s += __shfl_xor(s, o, 64); q += __shfl_xor(q, o, 64); }
    __shared__ float rs[2], rq[2];
    if ((t & 63) == 0) { rs[t >> 6] = s; rq[t >> 6] = q; }
    __syncthreads();
    if (t == 0) {
        float sm = rs[0] + rs[1], sq = rq[0] + rq[1];
        float mean = sm / (float)(SS * DD);
        float var = sq / (float)(SS * DD) - mean * mean;
        st[b * 2] = mean;
        st[b * 2 + 1] = rsqrtf(var + 1e-5f);
    }
}

// ---------------- LN apply, bf16 in -> bf16 out ----------------
__global__ void k_lnapplyb(const u16* __restrict__ X, const float* __restrict__ st,
                           u16* __restrict__ ob) {
    int b = blockIdx.y;
    long i = (long)b * (SS * DD) + ((long)blockIdx.x * 256 + threadIdx.x) * 8;
    const float mean = st[b * 2], rstd = st[b * 2 + 1];
    uint4 v = *(const uint4*)&X[i];
    uint32_t w[4] = { v.x, v.y, v.z, v.w };
    uint32_t r[4];
#pragma unroll
    for (int jj = 0; jj < 4; ++jj) {
        float a = (b2f((u16)(w[jj] & 0xffff)) - mean) * rstd;
        float c = (b2f((u16)(w[jj] >> 16)) - mean) * rstd;
        r[jj] = (uint32_t)f2b(a) | ((uint32_t)f2b(c) << 16);
    }
    *(uint4*)&ob[i] = make_uint4(r[0], r[1], r[2], r[3]);
}

// ---------------- column pool + LN-stats partials in ONE sweep of fout ----------------
__global__ void k_colpoolq(const u16* __restrict__ F, float* __restrict__ partc,
                           float* __restrict__ partq) {
    int dg = blockIdx.x, sc = blockIdx.y, b = blockIdx.z;
    int d = dg * 256 + threadIdx.x;
    const u16* fp = F + (long)b * (SS * DD) + (long)sc * 125 * DD + d;
    float s = 0.f, q = 0.f;
#pragma unroll 5
    for (int i = 0; i < 125; ++i) {
        float v = b2f(fp[(long)i * DD]);
        s += v; q = fmaf(v, v, q);
    }
    partc[((b * 8 + sc) * DD) + d] = s;
    partq[((b * 8 + sc) * DD) + d] = q;
}

// reduce colpool partials -> per-b mean/rstd
__global__ void k_stats2f(const float* __restrict__ partc, const float* __restrict__ partq,
                          float* __restrict__ st) {
    int b = blockIdx.x, t = threadIdx.x;
    float s = 0.f, q = 0.f;
    for (int i = t; i < 8 * DD; i += 256) {
        s += partc[b * 8 * DD + i];
        q += partq[b * 8 * DD + i];
    }
#pragma unroll
    for (int o = 32; o; o >>= 1) { s += __shfl_xor(s, o, 64); q += __shfl_xor(q, o, 64); }
    __shared__ float rs[4], rq[4];
    if ((t & 63) == 0) { rs[t >> 6] = s; rq[t >> 6] = q; }
    __syncthreads();
    if (t == 0) {
        float sm = rs[0] + rs[1] + rs[2] + rs[3];
        float sq = rq[0] + rq[1] + rq[2] + rq[3];
        float mean = sm / (float)(SS * DD);
        float var = sq / (float)(SS * DD) - mean * mean;
        st[b * 2] = mean;
        st[b * 2 + 1] = rsqrtf(var + 1e-5f);
    }
}

__global__ void k_colpool2(const float* __restrict__ partc, const float* __restrict__ st,
                           float* __restrict__ pooled) {
    int b = blockIdx.y, d = blockIdx.x * 256 + threadIdx.x;
    float s = 0.f;
#pragma unroll
    for (int c = 0; c < 8; ++c) s += partc[(b * 8 + c) * DD + d];
    pooled[b * DD + d] = (s * (1.0f / SS) - st[b * 2]) * st[b * 2 + 1];
}

// ---------------- output matvec, 2-stage parallel ----------------
__global__ void k_out1(const float* __restrict__ pooled, const float* __restrict__ Wout,
                       float* __restrict__ po) {
    const int og = blockIdx.x, dc = blockIdx.y, t = threadIdx.x;
    const int o = og * 256 + t;
    __shared__ float pl[8][32];
    pl[t >> 5][t & 31] = pooled[(t >> 5) * DD + dc * 32 + (t & 31)];
    __syncthreads();
    if (o >= OUTD) return;
    float acc[8] = {};
    for (int i = 0; i < 32; ++i) {
        float wv = Wout[(long)(dc * 32 + i) * OUTD + o];
#pragma unroll
        for (int bb = 0; bb < 8; ++bb) acc[bb] = fmaf(pl[bb][i], wv, acc[bb]);
    }
#pragma unroll
    for (int bb = 0; bb < 8; ++bb) po[(dc * 8 + bb) * OUTD + o] = acc[bb];
}
__global__ void k_out2(const float* __restrict__ po, float* __restrict__ out) {
    int b = blockIdx.y, o = blockIdx.x * 256 + threadIdx.x;
    if (o >= OUTD) return;
    float s = 0.f;
    for (int c = 0; c < 32; ++c) s += po[(c * 8 + b) * OUTD + o];
    out[b * OUTD + o] = s;
}

extern "C" void kernel_launch(void* const* d_in, const int* in_sizes, int n_in,
                              void* d_out, int out_size, void* d_ws, size_t ws_size,
                              hipStream_t stream) {
    const float* x    = (const float*)d_in[0];
    const float* Wq   = (const float*)d_in[1];
    const float* Wk   = (const float*)d_in[2];
    const float* Wv   = (const float*)d_in[3];
    const float* Wo   = (const float*)d_in[4];
    const float* W1   = (const float*)d_in[5];
    const float* b1   = (const float*)d_in[6];
    const float* W2   = (const float*)d_in[7];
    const float* b2   = (const float*)d_in[8];
    const float* Wout = (const float*)d_in[9];
    float* out = (float*)d_out;

    // ---- arena (~107.5 MB, proven size), lifetime-overlapped ----
    char* base = (char*)d_ws;
    u16*   xpe    = (u16*)(base);                    // @0: xpe -> ctx -> attnb -> fout(in-place)
    u16*   ctx    = xpe;
    u16*   attnb  = xpe;
    u16*   fout   = xpe;
    u16*   QKVb   = (u16*)(base + 16384000);         // @16.4: QKV 49.2MB -> hb [8000][4096] 65.5MB
    u16*   hb     = QKVb;
    u16*   Vt     = (u16*)(base + 65536000);         // @65.5: Vt 16.8MB -> aob -> partc/partq/po
    u16*   aob    = Vt;
    float* partc  = (float*)(base + 65536000);           // 256KB
    float* partq  = (float*)(base + 65536000 + 262144);  // 256KB
    float* po     = (float*)(base + 65536000 + 524288);  // 1MB
    char*  wbase  = base + 82313216;                 // @82.3: weights 25.2MB
    u16*   Wqkvt  = (u16*)(wbase);
    u16*   Wot    = (u16*)(wbase + 6291456);
    u16*   W1t    = (u16*)(wbase + 8388608);         //   [4096][1024]
    u16*   W2t    = (u16*)(wbase + 16777216);        //   [1024][4096]
    char*  mbase  = base + 107479040;
    float* part   = (float*)(mbase);
    float* st1    = (float*)(mbase + 8192);
    float* st2    = (float*)(mbase + 8448);
    float* pooled = (float*)(mbase + 8704);

    const float CEXP = 0.18033688f;   // 0.125 * log2(e), folded into Wq

    dim3 blk(256);
    // prep: posenc (y=6) runs concurrently with the 6 weight transposes (y=0..5)
    k_prep<<<dim3(16000, 7), dim3(32, 8), 0, stream>>>(x, xpe, Wq, Wk, Wv, Wo, W1, W2,
                                                       Wqkvt, Wot, W1t, W2t, CEXP);

    // QKV: A-resident (n-fastest), 8-wave BM=128 3-buf. 63m x 12n = 756 wgs.
    k_gemm<1, 128, 0, 1><<<dim3(756), dim3(512), 0, stream>>>(xpe, Wqkvt, QKVb, nullptr, nullptr,
                                                              8000, 3072, 1024, 1024, 1024, 3072, 12);
    k_vt<<<dim3(8, 16, 8), blk, 0, stream>>>(QKVb, Vt);

    // fused attention (writes ctx over xpe)
    k_flash<<<dim3(1024), blk, 0, stream>>>(QKVb, Vt, ctx);

    // Wo: 4-wave 128x128 (2 blocks/CU), n-fastest. 63m x 8n = 504 wgs.
    k_gemm4<1, 0, 1><<<dim3(504), blk, 0, stream>>>(ctx, Wot, aob, nullptr, nullptr,
                                                    8000, 1024, 1024, 1024, 1024, 1024, 8);
    k_stats1b<<<dim3(128, 8), blk, 0, stream>>>(aob, part);
    k_stats2<<<dim3(8), dim3(128), 0, stream>>>(part, st1);
    k_lnapplyb<<<dim3(500, 8), blk, 0, stream>>>(aob, st1, attnb);   // attnb over dead ctx

    // FFN1: 8-wave BM=256 2-buf (full-tile prologue issue), GROUPED 4m x 16n.
    k_gemm<2, 256, 2, 4><<<dim3(512), dim3(512), 0, stream>>>(attnb, W1t, hb, b1, nullptr,
                                                              8000, 4096, 1024, 1024, 1024, 4096, 16);
    // FFN2: 4-wave 128x128 (2 blocks/CU), GROUPED 8m x 8n.
    k_gemm4<3, 2, 8><<<dim3(504), blk, 0, stream>>>(hb, W2t, fout, b2, attnb,
                                                    8000, 1024, 4096, 4096, 4096, 1024, 8);

    // tail: single fout sweep produces colsum + sumsq partials; tiny reducers follow
    k_colpoolq<<<dim3(4, 8, 8), blk, 0, stream>>>(fout, partc, partq);
    k_stats2f<<<dim3(8), blk, 0, stream>>>(partc, partq, st2);
    k_colpool2<<<dim3(4, 8), blk, 0, stream>>>(partc, st2, pooled);
    k_out1<<<dim3(4, 32), blk, 0, stream>>>(pooled, Wout, po);
    k_out2<<<dim3(4, 8), blk, 0, stream>>>(po, out);
}

// Round 19
// 387.974 us; speedup vs baseline: 1.0345x; 1.0345x over previous
//
#include <hip/hip_runtime.h>
#include <stdint.h>
#include <math.h>

#define DD 1024
#define SS 1000
#define BB 8
#define HH 16
#define MIDD 4096
#define OUTD 1000

typedef unsigned short u16;
typedef __attribute__((ext_vector_type(4))) float f32x4;
typedef __attribute__((ext_vector_type(4))) unsigned int u32x4;

__device__ __forceinline__ u16 f2b(float f) {
    union { float f; uint32_t u; } v; v.f = f;
    uint32_t r = v.u + 0x7fffu + ((v.u >> 16) & 1u);
    return (u16)(r >> 16);
}
__device__ __forceinline__ float b2f(u16 b) {
    union { uint32_t u; float f; } v; v.u = ((uint32_t)b) << 16; return v.f;
}

// swizzled element offset for 64-elem (128B) rows: XOR 16B-chunk with row&7
__device__ __forceinline__ int sz64(int row, int e) {
    return row * 64 + ((((e >> 3) ^ row) & 7) << 3) + (e & 7);
}

__device__ __forceinline__ void mfma_b16(f32x4& d, u32x4 a, u32x4 b) {
    asm("v_mfma_f32_16x16x32_bf16 %0, %1, %2, %0" : "+v"(d) : "v"(a), "v"(b));
}
#define MFMA_FENCE() do { __builtin_amdgcn_sched_barrier(0); \
    asm volatile("s_nop 7\n\ts_nop 7\n\ts_nop 7" ::); \
    __builtin_amdgcn_sched_barrier(0); } while (0)

#define GLDS16(gp, lp) \
    __builtin_amdgcn_global_load_lds((const __attribute__((address_space(1))) uint32_t*)(gp), \
                                     (__attribute__((address_space(3))) uint32_t*)(lp), 16, 0, 0)

// XCD swizzle helper (m204 bijective form)
__device__ __forceinline__ int xcd_swz(int orig, int nwg) {
    const int q8 = nwg >> 3, r8 = nwg & 7, xc = orig & 7;
    return (xc < r8 ? xc * (q8 + 1) : r8 * (q8 + 1) + (xc - r8) * q8) + (orig >> 3);
}

// wg -> (bm_tile, bn_tile). ORDER 0: n-fastest. ORDER 1: m-fastest. ORDER 2: grouped.
template<int ORDER, int GM>
__device__ __forceinline__ void decode_wg(int wg, int tiles, int& mt, int& nt) {
    if (ORDER == 0)      { mt = wg / tiles; nt = wg % tiles; }
    else if (ORDER == 1) { mt = wg % tiles; nt = wg / tiles; }
    else {
        const int gsz = GM * tiles;
        const int grp = wg / gsz, idx = wg % gsz;
        nt = idx % tiles; mt = grp * GM + idx / tiles;
    }
}

// ---------------- posenc add + bf16 cast ----------------
__global__ void k_posenc(const float* __restrict__ x, u16* __restrict__ xpe) {
    long p = (long)blockIdx.x * 256 + threadIdx.x;
    if (p >= (long)BB * SS * DD / 2) return;
    int dp = (int)(p & (DD / 2 - 1));
    int s = (int)((p >> 9) % SS);
    float dv = __expf((float)(2 * dp) * (-9.210340371976184f / (float)DD));
    float sn, cs;
    sincosf((float)s * dv, &sn, &cs);
    float2 xv = *(const float2*)&x[p * 2];
    uint32_t pk = (uint32_t)f2b(xv.x + sn) | ((uint32_t)f2b(xv.y + cs) << 16);
    ((uint32_t*)xpe)[p] = pk;
}

// ---------------- ALL weight transposes in one launch ----------------
// blockIdx.y: 0=Wq(scaled) 1=Wk 2=Wv 3=Wo 4=W1 5=W2. Early-exit for small weights.
__global__ void k_wtall(const float* __restrict__ Wq, const float* __restrict__ Wk,
                        const float* __restrict__ Wv, const float* __restrict__ Wo,
                        const float* __restrict__ W1, const float* __restrict__ W2,
                        u16* __restrict__ Wqkvt, u16* __restrict__ Wot,
                        u16* __restrict__ W1t, u16* __restrict__ W2t, float qscale) {
    const int id = blockIdx.y;
    const float* W; u16* Wt; int R, C; float scale = 1.f;
    if (id == 0)      { W = Wq; Wt = Wqkvt;            R = 1024; C = 1024; scale = qscale; }
    else if (id == 1) { W = Wk; Wt = Wqkvt + 1048576;  R = 1024; C = 1024; }
    else if (id == 2) { W = Wv; Wt = Wqkvt + 2097152;  R = 1024; C = 1024; }
    else if (id == 3) { W = Wo; Wt = Wot;              R = 1024; C = 1024; }
    else if (id == 4) { W = W1; Wt = W1t;              R = 1024; C = 4096; }
    else              { W = W2; Wt = W2t;              R = 4096; C = 1024; }
    const int tilesx = C >> 5;
    const int ntile = (R >> 5) * tilesx;
    if (blockIdx.x >= (unsigned)ntile) return;
    const int bc = (blockIdx.x % tilesx) * 32, br = (blockIdx.x / tilesx) * 32;
    __shared__ float tile[32][33];
    int tx = threadIdx.x, ty = threadIdx.y;
#pragma unroll
    for (int i = 0; i < 32; i += 8)
        tile[ty + i][tx] = W[(long)(br + ty + i) * C + bc + tx];
    __syncthreads();
#pragma unroll
    for (int i = 0; i < 32; i += 8)
        Wt[(long)(bc + ty + i) * R + br + tx] = f2b(tile[tx][ty + i] * scale);
}

// ---------------- bf16 GEMM (8-wave, BN=256): C = A * Bt^T ----------------
// BM=128: 3-buf LDS (144KB), 2 tiles in flight, vmcnt(6).
// BM=256: 2-buf (128KB); FULL next tile (A+B, 8 loads) issued at loop top -> vmcnt(8).
// All LDS rows 128B with sz64 both-sides swizzle -> 0 bank conflicts (r15 lesson).
template<int MODE, int BM, int ORDER, int GM>
__global__ __launch_bounds__(512)
void k_gemm(const u16* __restrict__ A, const u16* __restrict__ Bt, void* __restrict__ Cp,
            const float* __restrict__ bias, const u16* res,
            int M, int N, int K, int lda, int ldb, int ldc, int tiles)
{
    constexpr int MF = BM / 32;
    constexpr int AL = BM / 64;
    constexpr int NBUF = (BM == 128) ? 3 : 2;
    __shared__ u16 SA[NBUF][BM * 64];
    __shared__ u16 SB[NBUF][256 * 64];
    const int t = threadIdx.x, lane = t & 63, w = t >> 6;
    const int lr = lane & 15, g = lane >> 4;
    const int wm = w >> 2, wn = w & 3;

    const int wg = xcd_swz(blockIdx.x, gridDim.x);
    int mt, ntl;
    decode_wg<ORDER, GM>(wg, tiles, mt, ntl);
    const int bm = mt * BM, bn = ntl * 256;

    const int srow8 = lane >> 3;
    const int csrc = ((lane & 7) ^ srow8) << 3;
    const u16* ga[AL];
    const u16* gb[4];
#pragma unroll
    for (int l = 0; l < AL; ++l) {
        int r = bm + w * (BM / 8) + l * 8 + srow8;
        if (r >= M) r = M - 1;
        ga[l] = A + (long)r * lda + csrc;
    }
#pragma unroll
    for (int l = 0; l < 4; ++l)
        gb[l] = Bt + (long)(bn + w * 32 + l * 8 + srow8) * ldb + csrc;

#define STAGE_A(buf, k0) do { \
        _Pragma("unroll") \
        for (int l = 0; l < AL; ++l) \
            GLDS16(ga[l] + (k0), &SA[buf][(w * (BM / 8) + l * 8) * 64]); \
    } while (0)
#define STAGE_B(buf, k0) do { \
        _Pragma("unroll") \
        for (int l = 0; l < 4; ++l) \
            GLDS16(gb[l] + (k0), &SB[buf][(w * 32 + l * 8) * 64]); \
    } while (0)

    f32x4 acc[MF][4] = {};

#define PH(buf, kk) do { \
        u32x4 av[MF], bv[4]; \
        _Pragma("unroll") \
        for (int m = 0; m < MF; ++m) \
            av[m] = *(const u32x4*)&SA[buf][sz64(wm * (BM / 2) + m * 16 + lr, (kk) * 32 + g * 8)]; \
        _Pragma("unroll") \
        for (int n = 0; n < 4; ++n) \
            bv[n] = *(const u32x4*)&SB[buf][sz64(wn * 64 + n * 16 + lr, (kk) * 32 + g * 8)]; \
        __builtin_amdgcn_s_setprio(1); \
        _Pragma("unroll") \
        for (int m = 0; m < MF; ++m) \
            _Pragma("unroll") \
            for (int n = 0; n < 4; ++n) \
                mfma_b16(acc[m][n], av[m], bv[n]); \
        __builtin_amdgcn_s_setprio(0); \
    } while (0)

    const int nt = K >> 6;

    if constexpr (NBUF == 3) {
        STAGE_A(0, 0); STAGE_B(0, 0);
        STAGE_A(1, 64); STAGE_B(1, 64);
        int cb = 0, sb = 2;
        for (int tt = 0; tt < nt; ++tt) {
            if (tt + 1 < nt) asm volatile("s_waitcnt vmcnt(6)" ::: "memory");
            else             asm volatile("s_waitcnt vmcnt(0)" ::: "memory");
            __builtin_amdgcn_s_barrier();
            if (tt + 2 < nt) { STAGE_A(sb, (tt + 2) << 6); STAGE_B(sb, (tt + 2) << 6); }
            PH(cb, 0);
            PH(cb, 1);
            cb = (cb == 2) ? 0 : cb + 1;
            sb = (sb == 2) ? 0 : sb + 1;
        }
    } else {
        // 2-buf, full-tile issue at top: ledger = 8 (tile tt) + 8 (tile tt+1) -> vmcnt(8)
        STAGE_A(0, 0); STAGE_B(0, 0);
        for (int tt = 0; tt < nt; ++tt) {
            const int cb2 = tt & 1, nb = cb2 ^ 1, kn = (tt + 1) << 6;
            if (tt + 1 < nt) {
                STAGE_A(nb, kn); STAGE_B(nb, kn);
                asm volatile("s_waitcnt vmcnt(8)" ::: "memory");
            } else {
                asm volatile("s_waitcnt vmcnt(0)" ::: "memory");
            }
            __builtin_amdgcn_s_barrier();
            PH(cb2, 0);
            PH(cb2, 1);
            __builtin_amdgcn_s_barrier();
        }
    }
#undef PH
#undef STAGE_A
#undef STAGE_B

    MFMA_FENCE();

#pragma unroll
    for (int m = 0; m < MF; ++m) {
#pragma unroll
        for (int j = 0; j < 4; ++j) {
            const int r = bm + wm * (BM / 2) + m * 16 + g * 4 + j;
            if (r >= M) continue;
            const long ro = (long)r * ldc;
#pragma unroll
            for (int n = 0; n < 4; ++n) {
                const int c = bn + wn * 64 + n * 16 + lr;
                float v = acc[m][n][j];
                if (MODE == 0)      ((float*)Cp)[ro + c] = v;
                else if (MODE == 1) ((u16*)Cp)[ro + c] = f2b(v);
                else if (MODE == 2) { v += bias[c]; ((u16*)Cp)[ro + c] = f2b(v > 0.f ? v : 0.f); }
                else                { v += bias[c] + b2f(res[ro + c]); ((u16*)Cp)[ro + c] = f2b(v); }
            }
        }
    }
}

// ---------------- bf16 GEMM (4-wave, 128x128, BK=64, 64KB LDS -> 2 blocks/CU) ----------------
template<int MODE, int ORDER, int GM>
__global__ __launch_bounds__(256)
void k_gemm4(const u16* __restrict__ A, const u16* __restrict__ Bt, void* __restrict__ Cp,
             const float* __restrict__ bias, const u16* res,
             int M, int N, int K, int lda, int ldb, int ldc, int tiles)
{
    __shared__ u16 SA[2][128 * 64];   // 32 KB
    __shared__ u16 SB[2][128 * 64];   // 32 KB
    const int t = threadIdx.x, lane = t & 63, w = t >> 6;   // 4 waves
    const int lr = lane & 15, g = lane >> 4;
    const int wm = w >> 1, wn = w & 1;

    const int wg = xcd_swz(blockIdx.x, gridDim.x);
    int mt, ntl;
    decode_wg<ORDER, GM>(wg, tiles, mt, ntl);
    const int bm = mt * 128, bn = ntl * 128;

    const int srow8 = lane >> 3;
    const int csrc = ((lane & 7) ^ srow8) << 3;
    const u16* ga[4];
    const u16* gb[4];
#pragma unroll
    for (int l = 0; l < 4; ++l) {
        int r = bm + w * 32 + l * 8 + srow8;
        if (r >= M) r = M - 1;
        ga[l] = A + (long)r * lda + csrc;
        gb[l] = Bt + (long)(bn + w * 32 + l * 8 + srow8) * ldb + csrc;
    }

#define STAGE_A(buf, k0) do { \
        _Pragma("unroll") \
        for (int l = 0; l < 4; ++l) \
            GLDS16(ga[l] + (k0), &SA[buf][(w * 32 + l * 8) * 64]); \
    } while (0)
#define STAGE_B(buf, k0) do { \
        _Pragma("unroll") \
        for (int l = 0; l < 4; ++l) \
            GLDS16(gb[l] + (k0), &SB[buf][(w * 32 + l * 8) * 64]); \
    } while (0)

    f32x4 acc[4][4] = {};

#define PH(buf, kk) do { \
        u32x4 av[4], bv[4]; \
        _Pragma("unroll") \
        for (int m = 0; m < 4; ++m) \
            av[m] = *(const u32x4*)&SA[buf][sz64(wm * 64 + m * 16 + lr, (kk) * 32 + g * 8)]; \
        _Pragma("unroll") \
        for (int n = 0; n < 4; ++n) \
            bv[n] = *(const u32x4*)&SB[buf][sz64(wn * 64 + n * 16 + lr, (kk) * 32 + g * 8)]; \
        __builtin_amdgcn_s_setprio(1); \
        _Pragma("unroll") \
        for (int m = 0; m < 4; ++m) \
            _Pragma("unroll") \
            for (int n = 0; n < 4; ++n) \
                mfma_b16(acc[m][n], av[m], bv[n]); \
        __builtin_amdgcn_s_setprio(0); \
    } while (0)

    const int nt = K >> 6;

    STAGE_A(0, 0); STAGE_B(0, 0);
    for (int tt = 0; tt < nt; ++tt) {
        const int cb = tt & 1, nb = cb ^ 1, kn = (tt + 1) << 6;
        if (tt + 1 < nt) {
            STAGE_A(nb, kn); STAGE_B(nb, kn);
            asm volatile("s_waitcnt vmcnt(8)" ::: "memory");
        } else {
            asm volatile("s_waitcnt vmcnt(0)" ::: "memory");
        }
        __builtin_amdgcn_s_barrier();
        PH(cb, 0);
        PH(cb, 1);
        __builtin_amdgcn_s_barrier();
    }
#undef PH
#undef STAGE_A
#undef STAGE_B

    MFMA_FENCE();

#pragma unroll
    for (int m = 0; m < 4; ++m) {
#pragma unroll
        for (int j = 0; j < 4; ++j) {
            const int r = bm + wm * 64 + m * 16 + g * 4 + j;
            if (r >= M) continue;
            const long ro = (long)r * ldc;
#pragma unroll
            for (int n = 0; n < 4; ++n) {
                const int c = bn + wn * 64 + n * 16 + lr;
                float v = acc[m][n][j];
                if (MODE == 0)      ((float*)Cp)[ro + c] = v;
                else if (MODE == 1) ((u16*)Cp)[ro + c] = f2b(v);
                else if (MODE == 2) { v += bias[c]; ((u16*)Cp)[ro + c] = f2b(v > 0.f ? v : 0.f); }
                else                { v += bias[c] + b2f(res[ro + c]); ((u16*)Cp)[ro + c] = f2b(v); }
            }
        }
    }
}

// ---------------- V part of QKV -> Vt [B*H][64][1024] (zero-pad s>=1000) ----------------
__global__ void k_vt(const u16* __restrict__ QKV, u16* __restrict__ Vt) {
    __shared__ u16 tile[128][80];
    int b = blockIdx.z, h = blockIdx.y, s0 = blockIdx.x * 128;
    int t = threadIdx.x;
    int rr = t >> 3, cc = (t & 7) * 8;
#pragma unroll
    for (int p = 0; p < 4; ++p) {
        int s = s0 + p * 32 + rr;
        uint4 val = make_uint4(0u, 0u, 0u, 0u);
        if (s < SS) val = *(const uint4*)&QKV[((long)(b * SS + s)) * 3072 + 2048 + h * 64 + cc];
        *(uint4*)&tile[p * 32 + rr][cc] = val;
    }
    __syncthreads();
    int d = t >> 2, sg = (t & 3) * 32;
    long base = ((long)((b * HH + h) * 64 + d)) * 1024 + s0 + sg;
#pragma unroll
    for (int i = 0; i < 4; ++i) {
        u16 tmp[8];
#pragma unroll
        for (int jj = 0; jj < 8; ++jj) tmp[jj] = tile[sg + i * 8 + jj][d];
        *(uint4*)&Vt[base + i * 8] = *(uint4*)tmp;
    }
}

// ---------------- fused flash attention, FIXED-MAX + SWAPPED QK^T ----------------
__global__ __launch_bounds__(256)
void k_flash(const u16* __restrict__ QKV, const u16* __restrict__ Vt, u16* __restrict__ ctx)
{
    __shared__ u16 Ps[128 * 64];
    __shared__ u16 Ks[64 * 64];
    __shared__ u16 Vs[64 * 64];
    __shared__ u16 Vones[16 * 64];
    const int t = threadIdx.x, lane = t & 63, wave = t >> 6;
    const int lr = lane & 15, g = lane >> 4;
    const int f = blockIdx.x;
    const int bh = (f & 7) + ((f >> 6) << 3);
    const int q0 = ((f >> 3) & 7) * 128;
    const int h = bh & 15, b = bh >> 4;
    const u16* Qg = QKV + (long)b * SS * 3072 + h * 64;
    const u16* Kg = Qg + 1024;
    const u16* Vg = Vt + (long)bh * 65536;

    const int sr8 = wave * 8 + (lane >> 3);
    const int ssrc = ((lane & 7) ^ (lane >> 3)) * 8;
    const int ldst0 = sr8 * 64 + (lane & 7) * 8;
    const int ldst1 = (32 + sr8) * 64 + (lane & 7) * 8;

#pragma unroll
    for (int r = 0; r < 4; ++r) {
        int qr = q0 + r * 32 + sr8; if (qr >= SS) qr = SS - 1;
        GLDS16(Qg + (long)qr * 3072 + ssrc, &Ps[(r * 32 + wave * 8) * 64]);
    }

    u32x4 kr0, kr1, vr0, vr1;
    {
        kr0 = *(const u32x4*)(Kg + (long)sr8 * 3072 + ssrc);
        kr1 = *(const u32x4*)(Kg + (long)(32 + sr8) * 3072 + ssrc);
        vr0 = *(const u32x4*)(Vg + (long)sr8 * 1024 + ssrc);
        vr1 = *(const u32x4*)(Vg + (long)(32 + sr8) * 1024 + ssrc);
    }

    __syncthreads();
    u32x4 qa[2][2];
#pragma unroll
    for (int m = 0; m < 2; ++m)
#pragma unroll
        for (int ks = 0; ks < 2; ++ks)
            qa[m][ks] = *(const u32x4*)&Ps[sz64(wave * 32 + m * 16 + lr, ks * 32 + g * 8)];

    *(u32x4*)&Ks[ldst0] = kr0;
    *(u32x4*)&Ks[ldst1] = kr1;
    *(u32x4*)&Vs[ldst0] = vr0;
    *(u32x4*)&Vs[ldst1] = vr1;
    for (int i = t; i < 16 * 64; i += 256)
        Vones[sz64(i >> 6, i & 63)] = ((i >> 6) == 0) ? (u16)0x3F80 : (u16)0;
    __syncthreads();

    f32x4 o[2][5] = {};

    for (int tt = 0; tt < 16; ++tt) {
        const int kt = tt * 64;
        if (tt < 15) {
            int a0 = kt + 64 + sr8;      if (a0 >= SS) a0 = SS - 1;
            int a1 = kt + 64 + 32 + sr8; if (a1 >= SS) a1 = SS - 1;
            kr0 = *(const u32x4*)(Kg + (long)a0 * 3072 + ssrc);
            kr1 = *(const u32x4*)(Kg + (long)a1 * 3072 + ssrc);
            vr0 = *(const u32x4*)(Vg + (long)sr8 * 1024 + kt + 64 + ssrc);
            vr1 = *(const u32x4*)(Vg + (long)(32 + sr8) * 1024 + kt + 64 + ssrc);
        }

        // swapped QK^T: s[n][m] = C[k = n*16+g*4+j][q = wave*32+m*16+lr]
        f32x4 s[4][2] = {};
#pragma unroll
        for (int ks = 0; ks < 2; ++ks) {
            u32x4 kb[4];
#pragma unroll
            for (int n = 0; n < 4; ++n)
                kb[n] = *(const u32x4*)&Ks[sz64(n * 16 + lr, ks * 32 + g * 8)];
            __builtin_amdgcn_s_setprio(1);
#pragma unroll
            for (int n = 0; n < 4; ++n)
#pragma unroll
                for (int m = 0; m < 2; ++m)
                    mfma_b16(s[n][m], kb[n], qa[m][ks]);
            __builtin_amdgcn_s_setprio(0);
        }
        MFMA_FENCE();

        if (tt == 15) {
#pragma unroll
            for (int n = 0; n < 4; ++n) {
                const int kbase = kt + n * 16 + g * 4;
#pragma unroll
                for (int j = 0; j < 4; ++j)
                    if (kbase + j >= SS) { s[n][0][j] = -1e30f; s[n][1][j] = -1e30f; }
            }
        }

        // P = exp2(s); consecutive k per thread -> pack pairs, ONE b64 store per (m,n)
#pragma unroll
        for (int m = 0; m < 2; ++m) {
            const int prow = wave * 32 + m * 16 + lr;
#pragma unroll
            for (int n = 0; n < 4; ++n) {
                float p0 = exp2f(s[n][m][0]);
                float p1 = exp2f(s[n][m][1]);
                float p2 = exp2f(s[n][m][2]);
                float p3 = exp2f(s[n][m][3]);
                uint32_t pk01, pk23;
                asm("v_cvt_pk_bf16_f32 %0, %1, %2" : "=v"(pk01) : "v"(p0), "v"(p1));
                asm("v_cvt_pk_bf16_f32 %0, %1, %2" : "=v"(pk23) : "v"(p2), "v"(p3));
                *(uint2*)&Ps[sz64(prow, n * 16 + g * 4)] = make_uint2(pk01, pk23);
            }
        }

        asm volatile("s_waitcnt lgkmcnt(0)" ::: "memory");
        __builtin_amdgcn_sched_barrier(0);

        // PV: o += P * V   (nd=4 reads the ones block -> denominator)
#pragma unroll
        for (int m = 0; m < 2; ++m) {
            u32x4 pa0 = *(const u32x4*)&Ps[sz64(wave * 32 + m * 16 + lr, g * 8)];
            u32x4 pa1 = *(const u32x4*)&Ps[sz64(wave * 32 + m * 16 + lr, 32 + g * 8)];
            __builtin_amdgcn_s_setprio(1);
#pragma unroll
            for (int nd = 0; nd < 4; ++nd) {
                u32x4 vb0 = *(const u32x4*)&Vs[sz64(nd * 16 + lr, g * 8)];
                u32x4 vb1 = *(const u32x4*)&Vs[sz64(nd * 16 + lr, 32 + g * 8)];
                mfma_b16(o[m][nd], pa0, vb0);
                mfma_b16(o[m][nd], pa1, vb1);
            }
            {
                u32x4 vb0 = *(const u32x4*)&Vones[sz64(lr, g * 8)];
                u32x4 vb1 = *(const u32x4*)&Vones[sz64(lr, 32 + g * 8)];
                mfma_b16(o[m][4], pa0, vb0);
                mfma_b16(o[m][4], pa1, vb1);
            }
            __builtin_amdgcn_s_setprio(0);
        }

        if (tt < 15) {
            __syncthreads();
            *(u32x4*)&Ks[ldst0] = kr0;
            *(u32x4*)&Ks[ldst1] = kr1;
            *(u32x4*)&Vs[ldst0] = vr0;
            *(u32x4*)&Vs[ldst1] = vr1;
            __syncthreads();
        }
    }

    MFMA_FENCE();

#pragma unroll
    for (int m = 0; m < 2; ++m)
#pragma unroll
        for (int j = 0; j < 4; ++j) {
            const int r = q0 + wave * 32 + m * 16 + g * 4 + j;
            if (r >= SS) continue;
            const float lval = __shfl(o[m][4][j], lane & 48);
            const float inv = 1.0f / lval;
#pragma unroll
            for (int nd = 0; nd < 4; ++nd)
                ctx[((long)b * SS + r) * 1024 + h * 64 + nd * 16 + lr] = f2b(o[m][nd][j] * inv);
        }
}

// ---------------- LN stats bf16 input (vectorized) ----------------
__global__ void k_stats1b(const u16* __restrict__ X, float* __restrict__ part) {
    int b = blockIdx.y, blk = blockIdx.x, t = threadIdx.x;
    const uint4* xp = (const uint4*)(X + (long)b * (SS * DD));
    float s = 0.f, q = 0.f;
    for (int i = blk * 256 + t; i < SS * DD / 8; i += 128 * 256) {
        uint4 v = xp[i];
        uint32_t w[4] = { v.x, v.y, v.z, v.w };
#pragma unroll
        for (int jj = 0; jj < 4; ++jj) {
            float a = b2f((u16)(w[jj] & 0xffff)), c = b2f((u16)(w[jj] >> 16));
            s += a + c; q += a * a + c * c;
        }
    }
#pragma unroll
    for (int o = 32; o; o >>= 1) { s += __shfl_xor(s, o, 64); q += __shfl_xor(q, o, 64); }
    __shared__ float rs[4], rq[4];
    if ((t & 63) == 0) { rs[t >> 6] = s; rq[t >> 6] = q; }
    __syncthreads();
    if (t == 0) {
        part[(b * 128 + blk) * 2]     = rs[0] + rs[1] + rs[2] + rs[3];
        part[(b * 128 + blk) * 2 + 1] = rq[0] + rq[1] + rq[2] + rq[3];
    }
}

__global__ void k_stats2(const float* __restrict__ part, float* __restrict__ st) {
    int b = blockIdx.x, t = threadIdx.x;
    float s = part[(b * 128 + t) * 2], q = part[(b * 128 + t) * 2 + 1];
#pragma unroll
    for (int o = 32; o; o >>= 1) { s += __shfl_xor(s, o, 64); q += __shfl_xor(q, o, 64); }
    __shared__ float rs[2], rq[2];
    if ((t & 63) == 0) { rs[t >> 6] = s; rq[t >> 6] = q; }
    __syncthreads();
    if (t == 0) {
        float sm = rs[0] + rs[1], sq = rq[0] + rq[1];
        float mean = sm / (float)(SS * DD);
        float var = sq / (float)(SS * DD) - mean * mean;
        st[b * 2] = mean;
        st[b * 2 + 1] = rsqrtf(var + 1e-5f);
    }
}

// ---------------- LN apply, bf16 in -> bf16 out ----------------
__global__ void k_lnapplyb(const u16* __restrict__ X, const float* __restrict__ st,
                           u16* __restrict__ ob) {
    int b = blockIdx.y;
    long i = (long)b * (SS * DD) + ((long)blockIdx.x * 256 + threadIdx.x) * 8;
    const float mean = st[b * 2], rstd = st[b * 2 + 1];
    uint4 v = *(const uint4*)&X[i];
    uint32_t w[4] = { v.x, v.y, v.z, v.w };
    uint32_t r[4];
#pragma unroll
    for (int jj = 0; jj < 4; ++jj) {
        float a = (b2f((u16)(w[jj] & 0xffff)) - mean) * rstd;
        float c = (b2f((u16)(w[jj] >> 16)) - mean) * rstd;
        r[jj] = (uint32_t)f2b(a) | ((uint32_t)f2b(c) << 16);
    }
    *(uint4*)&ob[i] = make_uint4(r[0], r[1], r[2], r[3]);
}

// ---------------- column pool + LN-stats partials in ONE sweep of fout ----------------
__global__ void k_colpoolq(const u16* __restrict__ F, float* __restrict__ partc,
                           float* __restrict__ partq) {
    int dg = blockIdx.x, sc = blockIdx.y, b = blockIdx.z;
    int d = dg * 256 + threadIdx.x;
    const u16* fp = F + (long)b * (SS * DD) + (long)sc * 125 * DD + d;
    float s = 0.f, q = 0.f;
#pragma unroll 5
    for (int i = 0; i < 125; ++i) {
        float v = b2f(fp[(long)i * DD]);
        s += v; q = fmaf(v, v, q);
    }
    partc[((b * 8 + sc) * DD) + d] = s;
    partq[((b * 8 + sc) * DD) + d] = q;
}

// reduce colpool partials -> per-b mean/rstd
__global__ void k_stats2f(const float* __restrict__ partc, const float* __restrict__ partq,
                          float* __restrict__ st) {
    int b = blockIdx.x, t = threadIdx.x;
    float s = 0.f, q = 0.f;
    for (int i = t; i < 8 * DD; i += 256) {
        s += partc[b * 8 * DD + i];
        q += partq[b * 8 * DD + i];
    }
#pragma unroll
    for (int o = 32; o; o >>= 1) { s += __shfl_xor(s, o, 64); q += __shfl_xor(q, o, 64); }
    __shared__ float rs[4], rq[4];
    if ((t & 63) == 0) { rs[t >> 6] = s; rq[t >> 6] = q; }
    __syncthreads();
    if (t == 0) {
        float sm = rs[0] + rs[1] + rs[2] + rs[3];
        float sq = rq[0] + rq[1] + rq[2] + rq[3];
        float mean = sm / (float)(SS * DD);
        float var = sq / (float)(SS * DD) - mean * mean;
        st[b * 2] = mean;
        st[b * 2 + 1] = rsqrtf(var + 1e-5f);
    }
}

__global__ void k_colpool2(const float* __restrict__ partc, const float* __restrict__ st,
                           float* __restrict__ pooled) {
    int b = blockIdx.y, d = blockIdx.x * 256 + threadIdx.x;
    float s = 0.f;
#pragma unroll
    for (int c = 0; c < 8; ++c) s += partc[(b * 8 + c) * DD + d];
    pooled[b * DD + d] = (s * (1.0f / SS) - st[b * 2]) * st[b * 2 + 1];
}

// ---------------- output matvec, 2-stage parallel ----------------
__global__ void k_out1(const float* __restrict__ pooled, const float* __restrict__ Wout,
                       float* __restrict__ po) {
    const int og = blockIdx.x, dc = blockIdx.y, t = threadIdx.x;
    const int o = og * 256 + t;
    __shared__ float pl[8][32];
    pl[t >> 5][t & 31] = pooled[(t >> 5) * DD + dc * 32 + (t & 31)];
    __syncthreads();
    if (o >= OUTD) return;
    float acc[8] = {};
    for (int i = 0; i < 32; ++i) {
        float wv = Wout[(long)(dc * 32 + i) * OUTD + o];
#pragma unroll
        for (int bb = 0; bb < 8; ++bb) acc[bb] = fmaf(pl[bb][i], wv, acc[bb]);
    }
#pragma unroll
    for (int bb = 0; bb < 8; ++bb) po[(dc * 8 + bb) * OUTD + o] = acc[bb];
}
__global__ void k_out2(const float* __restrict__ po, float* __restrict__ out) {
    int b = blockIdx.y, o = blockIdx.x * 256 + threadIdx.x;
    if (o >= OUTD) return;
    float s = 0.f;
    for (int c = 0; c < 32; ++c) s += po[(c * 8 + b) * OUTD + o];
    out[b * OUTD + o] = s;
}

extern "C" void kernel_launch(void* const* d_in, const int* in_sizes, int n_in,
                              void* d_out, int out_size, void* d_ws, size_t ws_size,
                              hipStream_t stream) {
    const float* x    = (const float*)d_in[0];
    const float* Wq   = (const float*)d_in[1];
    const float* Wk   = (const float*)d_in[2];
    const float* Wv   = (const float*)d_in[3];
    const float* Wo   = (const float*)d_in[4];
    const float* W1   = (const float*)d_in[5];
    const float* b1   = (const float*)d_in[6];
    const float* W2   = (const float*)d_in[7];
    const float* b2   = (const float*)d_in[8];
    const float* Wout = (const float*)d_in[9];
    float* out = (float*)d_out;

    // ---- arena (~107.5 MB, proven size), lifetime-overlapped ----
    char* base = (char*)d_ws;
    u16*   xpe    = (u16*)(base);                    // @0: xpe -> ctx -> attnb -> fout(in-place)
    u16*   ctx    = xpe;
    u16*   attnb  = xpe;
    u16*   fout   = xpe;
    u16*   QKVb   = (u16*)(base + 16384000);         // @16.4: QKV 49.2MB -> hb [8000][4096] 65.5MB
    u16*   hb     = QKVb;
    u16*   Vt     = (u16*)(base + 65536000);         // @65.5: Vt 16.8MB -> aob -> partc/partq/po
    u16*   aob    = Vt;
    float* partc  = (float*)(base + 65536000);           // 256KB
    float* partq  = (float*)(base + 65536000 + 262144);  // 256KB
    float* po     = (float*)(base + 65536000 + 524288);  // 1MB
    char*  wbase  = base + 82313216;                 // @82.3: weights 25.2MB
    u16*   Wqkvt  = (u16*)(wbase);
    u16*   Wot    = (u16*)(wbase + 6291456);
    u16*   W1t    = (u16*)(wbase + 8388608);         //   [4096][1024]
    u16*   W2t    = (u16*)(wbase + 16777216);        //   [1024][4096]
    char*  mbase  = base + 107479040;
    float* part   = (float*)(mbase);
    float* st1    = (float*)(mbase + 8192);
    float* st2    = (float*)(mbase + 8448);
    float* pooled = (float*)(mbase + 8704);

    const float CEXP = 0.18033688f;   // 0.125 * log2(e), folded into Wq

    dim3 blk(256);
    k_posenc<<<dim3(16000), blk, 0, stream>>>(x, xpe);
    k_wtall<<<dim3(4096, 6), dim3(32, 8), 0, stream>>>(Wq, Wk, Wv, Wo, W1, W2,
                                                       Wqkvt, Wot, W1t, W2t, CEXP);

    // QKV: A-resident (n-fastest), 8-wave BM=128 3-buf. 63m x 12n = 756 wgs.
    k_gemm<1, 128, 0, 1><<<dim3(756), dim3(512), 0, stream>>>(xpe, Wqkvt, QKVb, nullptr, nullptr,
                                                              8000, 3072, 1024, 1024, 1024, 3072, 12);
    k_vt<<<dim3(8, 16, 8), blk, 0, stream>>>(QKVb, Vt);

    // fused attention (writes ctx over xpe)
    k_flash<<<dim3(1024), blk, 0, stream>>>(QKVb, Vt, ctx);

    // Wo: 4-wave 128x128 (2 blocks/CU), n-fastest. 63m x 8n = 504 wgs.
    k_gemm4<1, 0, 1><<<dim3(504), blk, 0, stream>>>(ctx, Wot, aob, nullptr, nullptr,
                                                    8000, 1024, 1024, 1024, 1024, 1024, 8);
    k_stats1b<<<dim3(128, 8), blk, 0, stream>>>(aob, part);
    k_stats2<<<dim3(8), dim3(128), 0, stream>>>(part, st1);
    k_lnapplyb<<<dim3(500, 8), blk, 0, stream>>>(aob, st1, attnb);   // attnb over dead ctx

    // FFN1: 8-wave BM=256 2-buf (full-tile prologue issue), GROUPED 4m x 16n.
    k_gemm<2, 256, 2, 4><<<dim3(512), dim3(512), 0, stream>>>(attnb, W1t, hb, b1, nullptr,
                                                              8000, 4096, 1024, 1024, 1024, 4096, 16);
    // FFN2: 4-wave 128x128 (2 blocks/CU), GROUPED 8m x 8n.
    k_gemm4<3, 2, 8><<<dim3(504), blk, 0, stream>>>(hb, W2t, fout, b2, attnb,
                                                    8000, 1024, 4096, 4096, 4096, 1024, 8);

    // tail: single fout sweep produces colsum + sumsq partials; tiny reducers follow
    k_colpoolq<<<dim3(4, 8, 8), blk, 0, stream>>>(fout, partc, partq);
    k_stats2f<<<dim3(8), blk, 0, stream>>>(partc, partq, st2);
    k_colpool2<<<dim3(4, 8), blk, 0, stream>>>(partc, st2, pooled);
    k_out1<<<dim3(4, 32), blk, 0, stream>>>(pooled, Wout, po);
    k_out2<<<dim3(4, 8), blk, 0, stream>>>(po, out);
}